// Round 7
// baseline (295.804 us; speedup 1.0000x reference)
//
#include <hip/hip_runtime.h>

typedef unsigned short ushort_t;
typedef __attribute__((ext_vector_type(8))) short short8;
typedef __attribute__((ext_vector_type(4))) float f32x4;

__device__ __forceinline__ ushort_t f2b(float f) {           // RTN (accurate)
    union { float f; unsigned int i; } v; v.f = f;
    unsigned int x = v.i;
    return (ushort_t)((x + 0x7fffu + ((x >> 16) & 1u)) >> 16);
}
__device__ __forceinline__ ushort_t f2b_fast(float f) {      // round-half-up
    union { float f; unsigned int i; } v; v.f = f;
    return (ushort_t)((v.i + 0x8000u) >> 16);
}
__device__ __forceinline__ float exp2_hw(float x) {          // v_exp_f32: 2^x
    return __builtin_amdgcn_exp2f(x);
}
// async global->LDS DMA, 16B/lane: lane i reads 16B at its own gptr, writes
// LDS at (wave-uniform) lptr + i*16  [m97 recipe]
__device__ __forceinline__ void dma16(const ushort_t* g, ushort_t* l) {
    __builtin_amdgcn_global_load_lds(
        (const __attribute__((address_space(1))) unsigned int*)g,
        (__attribute__((address_space(3))) unsigned int*)l, 16, 0, 0);
}

// ---------------- fp32 -> bf16 conversion pre-pass ------------------------
__global__ __launch_bounds__(256)
void convert_bf16(const float* __restrict__ hs, const float* __restrict__ wq,
                  const float* __restrict__ wk, const float* __restrict__ wv,
                  const float* __restrict__ wo,
                  ushort_t* __restrict__ hsb, ushort_t* __restrict__ wqb,
                  ushort_t* __restrict__ wkb, ushort_t* __restrict__ wvb,
                  ushort_t* __restrict__ wob)
{
    const int y = blockIdx.y;
    const float* src; ushort_t* dst; int n;
    if (y == 0)      { src = hs; dst = hsb; n = 8192 * 768; }
    else if (y == 1) { src = wq; dst = wqb; n = 768 * 768; }
    else if (y == 2) { src = wk; dst = wkb; n = 768 * 768; }
    else if (y == 3) { src = wv; dst = wvb; n = 768 * 768; }
    else             { src = wo; dst = wob; n = 768 * 768; }
    const int idx = (blockIdx.x * 256 + threadIdx.x) * 8;
    if (idx >= n) return;
    const float4 a = ((const float4*)(src + idx))[0];
    const float4 b = ((const float4*)(src + idx))[1];
    ushort_t tmp[8] = { f2b(a.x), f2b(a.y), f2b(a.z), f2b(a.w),
                        f2b(b.x), f2b(b.y), f2b(b.z), f2b(b.w) };
    *(uint4*)(dst + idx) = *(const uint4*)tmp;
}

// ---------------- MFMA GEMM: BK=32, 3-buffer, COUNTED vmcnt (T3/T4) -------
// (kept from round 6: net ~+2us vs r2; gemm no longer in the top-5)
#define NIT 24    // 768 / BK(=32)

template<int MODE>
__global__ __launch_bounds__(256, 3)
void gemm_mfma(const ushort_t* __restrict__ A,
               const ushort_t* __restrict__ W0, const ushort_t* __restrict__ W1,
               const ushort_t* __restrict__ W2,
               const float* __restrict__ b0, const float* __restrict__ b1,
               const float* __restrict__ b2,
               void* __restrict__ C0, void* __restrict__ C1, void* __restrict__ C2)
{
    __shared__ __attribute__((aligned(16))) ushort_t Ab[3][128 * 32];
    __shared__ __attribute__((aligned(16))) ushort_t Wb[3][128 * 32];

    const int id   = blockIdx.x;
    const int xcd  = id & 7;
    const int slot = id >> 3;
    int mtile, otile, z;
    if (MODE == 0) {
        mtile = (slot / 18) * 8 + xcd;
        const int rem = slot % 18;
        otile = rem % 6;
        z     = rem / 6;
    } else {
        mtile = (slot / 6) * 8 + xcd;
        otile = slot % 6;
        z     = 0;
    }
    const ushort_t* W = (z == 0) ? W0 : (z == 1) ? W1 : W2;
    const float* bias  = (z == 0) ? b0 : (z == 1) ? b1 : b2;
    void* C            = (z == 0) ? C0 : (z == 1) ? C1 : C2;

    const int t    = threadIdx.x;
    const int lane = t & 63;
    const int w    = t >> 6;
    const int col  = lane & 15;
    const int kg   = lane >> 4;
    const int m0   = mtile * 128;
    const int o0   = otile * 128;
    const int mh   = (w & 1) * 64;
    const int oh   = (w >> 1) * 64;

    f32x4 acc[4][4];
#pragma unroll
    for (int mt = 0; mt < 4; ++mt)
#pragma unroll
        for (int nt = 0; nt < 4; ++nt) acc[mt][nt] = (f32x4){0.f, 0.f, 0.f, 0.f};

    const int lrow = lane >> 2;                       // 0..15
    const int lgr  = (lane & 3) ^ ((lane >> 3) & 3);  // source granule
    const ushort_t* pa = A + (size_t)(m0 + lrow) * 768 + lgr * 8;
    const ushort_t* pw = W + (size_t)(o0 + lrow) * 768 + lgr * 8;

    auto stage = [&](int c, int b) {
#pragma unroll
        for (int j = 0; j < 2; ++j) {
            const int q = 2 * w + j;
            dma16(pa + (size_t)q * (16 * 768) + c * 32, &Ab[b][q * 512]);
            dma16(pw + (size_t)q * (16 * 768) + c * 32, &Wb[b][q * 512]);
        }
    };

    const int gq = (kg ^ ((col >> 1) & 3)) * 8;

    auto step = [&](int it, int cur, int nb) {
        __builtin_amdgcn_s_barrier();      // all waves done reading buf[nb]
        if (it + 2 < NIT) {
            stage(it + 2, nb);             // chunks it+1,it+2 stay in flight
            asm volatile("s_waitcnt vmcnt(8)" ::: "memory");   // chunk it landed
        } else if (it + 1 < NIT) {
            asm volatile("s_waitcnt vmcnt(4)" ::: "memory");
        } else {
            asm volatile("s_waitcnt vmcnt(0)" ::: "memory");
        }
        __builtin_amdgcn_sched_barrier(0);

        short8 wf[4], af[4];
#pragma unroll
        for (int nt = 0; nt < 4; ++nt)
            wf[nt] = *(const short8*)&Wb[cur][(oh + nt * 16 + col) * 32 + gq];
#pragma unroll
        for (int mt = 0; mt < 4; ++mt)
            af[mt] = *(const short8*)&Ab[cur][(mh + mt * 16 + col) * 32 + gq];

#pragma unroll
        for (int mt = 0; mt < 4; ++mt)
#pragma unroll
            for (int nt = 0; nt < 4; ++nt)
                acc[mt][nt] = __builtin_amdgcn_mfma_f32_16x16x32_bf16(
                    af[mt], wf[nt], acc[mt][nt], 0, 0, 0);
    };

    stage(0, 0);   // prologue: chunks 0,1 -> 8 ops outstanding
    stage(1, 1);
    for (int j = 0; j < NIT; j += 3) {     // static buffer rotation
        step(j + 0, 0, 2);
        step(j + 1, 1, 0);
        step(j + 2, 2, 1);
    }

    float bias_v[4];
#pragma unroll
    for (int nt = 0; nt < 4; ++nt) bias_v[nt] = bias[o0 + oh + nt * 16 + col];
    const float scale = (MODE == 0 && z == 0) ? 0.18033688011112042f : 1.0f;

#pragma unroll
    for (int mt = 0; mt < 4; ++mt)
#pragma unroll
        for (int nt = 0; nt < 4; ++nt) {
            const int mb = m0 + mh + mt * 16 + kg * 4;
            const int o  = o0 + oh + nt * 16 + col;
            if (MODE == 0 && z == 2) {
                ushort_t tmp[4];
#pragma unroll
                for (int r = 0; r < 4; ++r) tmp[r] = f2b(acc[mt][nt][r] + bias_v[nt]);
                const size_t dst = ((size_t)((mb >> 11) * 12 + (o >> 6)) << 17)
                                 + ((size_t)(o & 63) << 11) + (mb & 2047);
                *(uint2*)((ushort_t*)C + dst) = *(const uint2*)tmp;
            } else {
#pragma unroll
                for (int r = 0; r < 4; ++r) {
                    const int m = mb + r;
                    const float v = (acc[mt][nt][r] + bias_v[nt]) * scale;
                    if (MODE == 0) {
                        const size_t dst = ((size_t)((m >> 11) * 12 + (o >> 6)) << 17)
                                         + ((size_t)(m & 2047) << 6) + (o & 63);
                        ((ushort_t*)C)[dst] = f2b(v);
                    } else {
                        ((float*)C)[(size_t)m * 768 + o] = v;
                    }
                }
            }
        }
}

// ---------------- MFMA flash attention, KVBLK=128 rounds ------------------
// Q: [48][2048][64] bf16 pre-scaled by 0.125*log2e. K: [48][2048][64].
// Vt: [48][64][2048]. AO: [4][2048][768] bf16.
// ROUND-7: r2 structure measured ~5700 cyc per 64-key chunk-round vs ~1800
// cyc of pipe demand -> round overhead (2 barriers + chained latencies)
// dominates. Amortize: each round now stages 128 keys (K[128][64],
// V[64][128], 32KB), prefetches once, pays 2 barriers, computes two 64-key
// sub-chunks. Rounds/block: 33 -> 17. PS_STRIDE reverted to 76 (78 was
// measured WORSE: conflicts 6.49M -> 9.73M). LDS 45.6KB -> 3 blocks/CU.
// Pairing (31-p, p) kept: still uniform 16.5 rounds/block.
#define KSTR 72        // K row stride (64 d + pad), ushorts
#define VSTR 136       // V row stride (128 keys + pad), ushorts
#define PS_STRIDE 76

__global__ __launch_bounds__(256, 3)
void attn_mfma(const ushort_t* __restrict__ Q, const ushort_t* __restrict__ K,
               const ushort_t* __restrict__ Vt, ushort_t* __restrict__ AO)
{
    __shared__ ushort_t Ks[128 * KSTR];            // K rounds [key][d]
    __shared__ ushort_t Vs[64 * VSTR];             // V rounds [d][key]
    __shared__ ushort_t Ps[4][16 * PS_STRIDE];     // per-wave P tile [q][key]

    const int t    = threadIdx.x;
    const int lane = t & 63;
    const int w    = t >> 6;
    const int id   = blockIdx.x;
    const int bh   = ((id >> 3) >> 4) * 8 + (id & 7);   // 16 blocks/bh on one XCD
    const int p    = (id >> 3) & 15;                    // pair id 0..15
    const size_t base = (size_t)bh << 17;

    const int col = lane & 15;
    const int kg  = lane >> 4;
    const int b = bh / 12, h = bh % 12;

    // staging geometry (per thread 64B of K and 64B of V per round)
    const int krow = t >> 1;            // K row 0..127
    const int kcol = (t & 1) * 32;      // ushort col 0/32
    const int vrow = t >> 2;            // V d-row 0..63
    const int vcol = (t & 3) * 32;      // ushort col 0/32/64/96

#pragma unroll
    for (int phase = 0; phase < 2; ++phase) {
        const int tile = phase ? p : (31 - p);     // heavy tile first
        const int q0   = tile << 6;
        const int nch  = tile + 1;                 // 64-key chunks
        const int nrd  = (nch + 1) >> 1;           // 128-key rounds

        // Q A-frag for this wave's 16 rows
        const ushort_t* pq = Q + base + (size_t)(q0 + 16 * w + col) * 64 + kg * 8;
        const short8 aq0 = *(const short8*)pq;
        const short8 aq1 = *(const short8*)(pq + 32);

        float l_lane[4] = {0.f, 0.f, 0.f, 0.f};
        f32x4 o_acc[4];
#pragma unroll
        for (int vt = 0; vt < 4; ++vt) o_acc[vt] = (f32x4){0.f, 0.f, 0.f, 0.f};

        const int qrow = q0 + 16 * w + 4 * kg;

        uint4 kr[4], vr[4];
        auto pref = [&](int r) {   // never OOB: nrd*128 <= 2048 for all tiles
            const ushort_t* pk = K  + base + (size_t)(r * 128 + krow) * 64 + kcol;
            const ushort_t* pv = Vt + base + ((size_t)vrow << 11) + r * 128 + vcol;
#pragma unroll
            for (int j = 0; j < 4; ++j) {
                kr[j] = *(const uint4*)(pk + j * 8);
                vr[j] = *(const uint4*)(pv + j * 8);
            }
        };

        // one 64-key sub-chunk: QK^T -> softmax-partial -> Ps -> PV
        auto csub = [&](int c, int sub) {
            f32x4 s[4];
            __builtin_amdgcn_s_setprio(1);
#pragma unroll
            for (int kt = 0; kt < 4; ++kt) {
                const ushort_t* pkf =
                    &Ks[(sub * 64 + kt * 16 + col) * KSTR + kg * 8];
                const short8 b0 = *(const short8*)pkf;
                const short8 b1 = *(const short8*)(pkf + 32);
                f32x4 acc = (f32x4){0.f, 0.f, 0.f, 0.f};
                acc = __builtin_amdgcn_mfma_f32_16x16x32_bf16(aq0, b0, acc, 0, 0, 0);
                acc = __builtin_amdgcn_mfma_f32_16x16x32_bf16(aq1, b1, acc, 0, 0, 0);
                s[kt] = acc;
            }
            __builtin_amdgcn_s_setprio(0);

            if (c == nch - 1) {            // diagonal chunk: causal mask
                const int k0 = c << 6;
#pragma unroll
                for (int kt = 0; kt < 4; ++kt)
#pragma unroll
                    for (int r = 0; r < 4; ++r) {
                        const int key = k0 + kt * 16 + col;
                        s[kt][r] = (key > qrow + r) ? 0.f : exp2_hw(s[kt][r]);
                    }
            } else {
#pragma unroll
                for (int kt = 0; kt < 4; ++kt)
#pragma unroll
                    for (int r = 0; r < 4; ++r) s[kt][r] = exp2_hw(s[kt][r]);
            }
#pragma unroll
            for (int r = 0; r < 4; ++r)
                l_lane[r] += (s[0][r] + s[1][r]) + (s[2][r] + s[3][r]);

            // P: C-layout -> LDS -> A-layout (wave-internal)
            ushort_t* ps = Ps[w];
#pragma unroll
            for (int kt = 0; kt < 4; ++kt)
#pragma unroll
                for (int r = 0; r < 4; ++r)
                    ps[(4 * kg + r) * PS_STRIDE + kt * 16 + col] = f2b_fast(s[kt][r]);
            short8 pa0, pa1;
            {
                const ushort_t* pp = ps + (size_t)col * PS_STRIDE + kg * 8;
                pa0 = *(const short8*)pp;
                pa1 = *(const short8*)(pp + 32);
            }

            __builtin_amdgcn_s_setprio(1);
#pragma unroll
            for (int vt = 0; vt < 4; ++vt) {
                const ushort_t* pvf =
                    &Vs[(vt * 16 + col) * VSTR + sub * 64 + kg * 8];
                const short8 v0 = *(const short8*)pvf;
                const short8 v1 = *(const short8*)(pvf + 32);
                f32x4 o = o_acc[vt];
                o = __builtin_amdgcn_mfma_f32_16x16x32_bf16(pa0, v0, o, 0, 0, 0);
                o = __builtin_amdgcn_mfma_f32_16x16x32_bf16(pa1, v1, o, 0, 0, 0);
                o_acc[vt] = o;
            }
            __builtin_amdgcn_s_setprio(0);
        };

        pref(0);   // prologue prefetch

        for (int r = 0; r < nrd; ++r) {
            __syncthreads();   // prior round's LDS reads complete
#pragma unroll
            for (int j = 0; j < 4; ++j) {
                *(uint4*)&Ks[krow * KSTR + kcol + j * 8] = kr[j];
                *(uint4*)&Vs[vrow * VSTR + vcol + j * 8] = vr[j];
            }
            __syncthreads();   // round staged

            if (r + 1 < nrd) pref(r + 1);   // flies over the round's compute

            const int c0 = 2 * r;
            csub(c0, 0);
            if (c0 + 1 < nch) csub(c0 + 1, 1);
        }

        // l reduction (once per phase) + normalize + store
        float linv[4];
#pragma unroll
        for (int r = 0; r < 4; ++r) {
            float ls = l_lane[r];
            ls += __shfl_xor(ls, 1);
            ls += __shfl_xor(ls, 2);
            ls += __shfl_xor(ls, 4);
            ls += __shfl_xor(ls, 8);
            linv[r] = 1.f / ls;
        }
#pragma unroll
        for (int vt = 0; vt < 4; ++vt)
#pragma unroll
            for (int r = 0; r < 4; ++r) {
                const int q = q0 + 16 * w + 4 * kg + r;
                AO[((size_t)(b * 2048 + q)) * 768 + h * 64 + vt * 16 + col] =
                    f2b_fast(o_acc[vt][r] * linv[r]);
            }
    }
}

extern "C" void kernel_launch(void* const* d_in, const int* in_sizes, int n_in,
                              void* d_out, int out_size, void* d_ws, size_t ws_size,
                              hipStream_t stream) {
    const float* hs = (const float*)d_in[0];
    const float* wq = (const float*)d_in[1];
    const float* bq = (const float*)d_in[2];
    const float* wk = (const float*)d_in[3];
    const float* bk = (const float*)d_in[4];
    const float* wv = (const float*)d_in[5];
    const float* bv = (const float*)d_in[6];
    const float* wo = (const float*)d_in[7];
    const float* bo = (const float*)d_in[8];
    float* out = (float*)d_out;

    const size_t NB = (size_t)8192 * 768;
    const size_t WN = (size_t)768 * 768;
    ushort_t* hsb = (ushort_t*)d_ws;        // aliased: becomes AO after QKV GEMMs
    ushort_t* Qb  = hsb + NB;
    ushort_t* Kb  = Qb + NB;
    ushort_t* Vtb = Kb + NB;                // V transposed [48][64][2048]
    ushort_t* wqb = Vtb + NB;
    ushort_t* wkb = wqb + WN;
    ushort_t* wvb = wkb + WN;
    ushort_t* wob = wvb + WN;
    ushort_t* AO  = hsb;                    // hs_bf16 dead once attn runs

    dim3 blk(256);
    convert_bf16<<<dim3(3072, 5), blk, 0, stream>>>(hs, wq, wk, wv, wo,
                                                    hsb, wqb, wkb, wvb, wob);
    gemm_mfma<0><<<dim3(1152), blk, 0, stream>>>(hsb, wqb, wkb, wvb,
                                                 bq, bk, bv, Qb, Kb, Vtb);
    attn_mfma<<<dim3(768), blk, 0, stream>>>(Qb, Kb, Vtb, AO);
    gemm_mfma<1><<<dim3(384), blk, 0, stream>>>(AO, wob, wob, wob,
                                                bo, bo, bo, out, out, out);
}

// Round 9
// 208.887 us; speedup vs baseline: 1.4161x; 1.4161x over previous
//
#include <hip/hip_runtime.h>

typedef unsigned short ushort_t;
typedef __attribute__((ext_vector_type(8))) short short8;
typedef __attribute__((ext_vector_type(4))) float f32x4;

__device__ __forceinline__ ushort_t f2b(float f) {           // RTN (accurate)
    union { float f; unsigned int i; } v; v.f = f;
    unsigned int x = v.i;
    return (ushort_t)((x + 0x7fffu + ((x >> 16) & 1u)) >> 16);
}
__device__ __forceinline__ ushort_t f2b_fast(float f) {      // round-half-up
    union { float f; unsigned int i; } v; v.f = f;
    return (ushort_t)((v.i + 0x8000u) >> 16);
}
__device__ __forceinline__ float exp2_hw(float x) {          // v_exp_f32: 2^x
    return __builtin_amdgcn_exp2f(x);
}
// async global->LDS DMA, 16B/lane: lane i reads 16B at its own gptr, writes
// LDS at (wave-uniform) lptr + i*16  [m97 recipe]
__device__ __forceinline__ void dma16(const ushort_t* g, ushort_t* l) {
    __builtin_amdgcn_global_load_lds(
        (const __attribute__((address_space(1))) unsigned int*)g,
        (__attribute__((address_space(3))) unsigned int*)l, 16, 0, 0);
}

// ---------------- fp32 -> bf16 conversion pre-pass ------------------------
__global__ __launch_bounds__(256)
void convert_bf16(const float* __restrict__ hs, const float* __restrict__ wq,
                  const float* __restrict__ wk, const float* __restrict__ wv,
                  const float* __restrict__ wo,
                  ushort_t* __restrict__ hsb, ushort_t* __restrict__ wqb,
                  ushort_t* __restrict__ wkb, ushort_t* __restrict__ wvb,
                  ushort_t* __restrict__ wob)
{
    const int y = blockIdx.y;
    const float* src; ushort_t* dst; int n;
    if (y == 0)      { src = hs; dst = hsb; n = 8192 * 768; }
    else if (y == 1) { src = wq; dst = wqb; n = 768 * 768; }
    else if (y == 2) { src = wk; dst = wkb; n = 768 * 768; }
    else if (y == 3) { src = wv; dst = wvb; n = 768 * 768; }
    else             { src = wo; dst = wob; n = 768 * 768; }
    const int idx = (blockIdx.x * 256 + threadIdx.x) * 8;
    if (idx >= n) return;
    const float4 a = ((const float4*)(src + idx))[0];
    const float4 b = ((const float4*)(src + idx))[1];
    ushort_t tmp[8] = { f2b(a.x), f2b(a.y), f2b(a.z), f2b(a.w),
                        f2b(b.x), f2b(b.y), f2b(b.z), f2b(b.w) };
    *(uint4*)(dst + idx) = *(const uint4*)tmp;
}

// ---------------- MFMA GEMM: BK=32, 3-buffer, COUNTED vmcnt (T3/T4) -------
// (kept from round 6: verified ~2us better than r2 gemm; out of the top-5)
#define NIT 24    // 768 / BK(=32)

template<int MODE>
__global__ __launch_bounds__(256, 3)
void gemm_mfma(const ushort_t* __restrict__ A,
               const ushort_t* __restrict__ W0, const ushort_t* __restrict__ W1,
               const ushort_t* __restrict__ W2,
               const float* __restrict__ b0, const float* __restrict__ b1,
               const float* __restrict__ b2,
               void* __restrict__ C0, void* __restrict__ C1, void* __restrict__ C2)
{
    __shared__ __attribute__((aligned(16))) ushort_t Ab[3][128 * 32];
    __shared__ __attribute__((aligned(16))) ushort_t Wb[3][128 * 32];

    const int id   = blockIdx.x;
    const int xcd  = id & 7;
    const int slot = id >> 3;
    int mtile, otile, z;
    if (MODE == 0) {
        mtile = (slot / 18) * 8 + xcd;
        const int rem = slot % 18;
        otile = rem % 6;
        z     = rem / 6;
    } else {
        mtile = (slot / 6) * 8 + xcd;
        otile = slot % 6;
        z     = 0;
    }
    const ushort_t* W = (z == 0) ? W0 : (z == 1) ? W1 : W2;
    const float* bias  = (z == 0) ? b0 : (z == 1) ? b1 : b2;
    void* C            = (z == 0) ? C0 : (z == 1) ? C1 : C2;

    const int t    = threadIdx.x;
    const int lane = t & 63;
    const int w    = t >> 6;
    const int col  = lane & 15;
    const int kg   = lane >> 4;
    const int m0   = mtile * 128;
    const int o0   = otile * 128;
    const int mh   = (w & 1) * 64;
    const int oh   = (w >> 1) * 64;

    f32x4 acc[4][4];
#pragma unroll
    for (int mt = 0; mt < 4; ++mt)
#pragma unroll
        for (int nt = 0; nt < 4; ++nt) acc[mt][nt] = (f32x4){0.f, 0.f, 0.f, 0.f};

    const int lrow = lane >> 2;                       // 0..15
    const int lgr  = (lane & 3) ^ ((lane >> 3) & 3);  // source granule
    const ushort_t* pa = A + (size_t)(m0 + lrow) * 768 + lgr * 8;
    const ushort_t* pw = W + (size_t)(o0 + lrow) * 768 + lgr * 8;

    auto stage = [&](int c, int b) {
#pragma unroll
        for (int j = 0; j < 2; ++j) {
            const int q = 2 * w + j;
            dma16(pa + (size_t)q * (16 * 768) + c * 32, &Ab[b][q * 512]);
            dma16(pw + (size_t)q * (16 * 768) + c * 32, &Wb[b][q * 512]);
        }
    };

    const int gq = (kg ^ ((col >> 1) & 3)) * 8;

    auto step = [&](int it, int cur, int nb) {
        __builtin_amdgcn_s_barrier();      // all waves done reading buf[nb]
        if (it + 2 < NIT) {
            stage(it + 2, nb);             // chunks it+1,it+2 stay in flight
            asm volatile("s_waitcnt vmcnt(8)" ::: "memory");   // chunk it landed
        } else if (it + 1 < NIT) {
            asm volatile("s_waitcnt vmcnt(4)" ::: "memory");
        } else {
            asm volatile("s_waitcnt vmcnt(0)" ::: "memory");
        }
        __builtin_amdgcn_sched_barrier(0);

        short8 wf[4], af[4];
#pragma unroll
        for (int nt = 0; nt < 4; ++nt)
            wf[nt] = *(const short8*)&Wb[cur][(oh + nt * 16 + col) * 32 + gq];
#pragma unroll
        for (int mt = 0; mt < 4; ++mt)
            af[mt] = *(const short8*)&Ab[cur][(mh + mt * 16 + col) * 32 + gq];

#pragma unroll
        for (int mt = 0; mt < 4; ++mt)
#pragma unroll
            for (int nt = 0; nt < 4; ++nt)
                acc[mt][nt] = __builtin_amdgcn_mfma_f32_16x16x32_bf16(
                    af[mt], wf[nt], acc[mt][nt], 0, 0, 0);
    };

    stage(0, 0);   // prologue: chunks 0,1 -> 8 ops outstanding
    stage(1, 1);
    for (int j = 0; j < NIT; j += 3) {     // static buffer rotation
        step(j + 0, 0, 2);
        step(j + 1, 1, 0);
        step(j + 2, 2, 1);
    }

    float bias_v[4];
#pragma unroll
    for (int nt = 0; nt < 4; ++nt) bias_v[nt] = bias[o0 + oh + nt * 16 + col];
    const float scale = (MODE == 0 && z == 0) ? 0.18033688011112042f : 1.0f;

#pragma unroll
    for (int mt = 0; mt < 4; ++mt)
#pragma unroll
        for (int nt = 0; nt < 4; ++nt) {
            const int mb = m0 + mh + mt * 16 + kg * 4;
            const int o  = o0 + oh + nt * 16 + col;
            if (MODE == 0 && z == 2) {
                ushort_t tmp[4];
#pragma unroll
                for (int r = 0; r < 4; ++r) tmp[r] = f2b(acc[mt][nt][r] + bias_v[nt]);
                const size_t dst = ((size_t)((mb >> 11) * 12 + (o >> 6)) << 17)
                                 + ((size_t)(o & 63) << 11) + (mb & 2047);
                *(uint2*)((ushort_t*)C + dst) = *(const uint2*)tmp;
            } else {
#pragma unroll
                for (int r = 0; r < 4; ++r) {
                    const int m = mb + r;
                    const float v = (acc[mt][nt][r] + bias_v[nt]) * scale;
                    if (MODE == 0) {
                        const size_t dst = ((size_t)((m >> 11) * 12 + (o >> 6)) << 17)
                                         + ((size_t)(m & 2047) << 6) + (o & 63);
                        ((ushort_t*)C)[dst] = f2b(v);
                    } else {
                        ((float*)C)[(size_t)m * 768 + o] = v;
                    }
                }
            }
        }
}

// ---------------- MFMA flash attention, swapped-QK^T in-register P --------
// Q: [48][2048][64] bf16 pre-scaled by 0.125*log2e. K: [48][2048][64].
// Vt: [48][64][2048]. AO: [4][2048][768] bf16.
// ROUND-9 (= r8 resubmit after infra failure; dead placeholder code removed).
// r2 structure (76.6us proven), ONE work-reducing change (T12 for 16x16):
// compute S^T = mfma(K,Q) so lane (col,kg) holds S for q=col and keys
// {16kt+4kg+r}. Softmax l is lane-local; P->PV-A-frag is in-register:
// 8 cvt_pk_bf16 + 12 shfl_xor(16/32/48) + selects. Removes the Ps LDS
// round-trip (16KB/chunk LDS traffic + 2 serial LDS waits + conflicts).
// Exchange table (re-verified case-by-case for kg=0..3):
//   X16 = kg<2 ? kt{0,2} : kt{1,3};  X32 = kg<2 ? kt{1,3} : kt{0,2}
//   R16=shfl_xor(X16,16)  R32=shfl_xor(X32,32)  R48=shfl_xor(X32,48)
//   F = [X16,R48,R32,R16][kg]  (keys kg*8..kg*8+7    -> pa0)
//   S = [R16,R32,R48,X16][kg]  (keys 32+kg*8..+7     -> pa1)
//   pa0 = [F0,F1,S0,S1], pa1 = [F2,F3,S2,S3]
#define KV_STRIDE 72

__global__ __launch_bounds__(256, 3)
void attn_mfma(const ushort_t* __restrict__ Q, const ushort_t* __restrict__ K,
               const ushort_t* __restrict__ Vt, ushort_t* __restrict__ AO)
{
    __shared__ ushort_t Ks[64 * KV_STRIDE];        // K chunk [key][d]
    __shared__ ushort_t Vs[64 * KV_STRIDE];        // V chunk [d][key]

    const int t    = threadIdx.x;
    const int lane = t & 63;
    const int w    = t >> 6;
    const int id   = blockIdx.x;
    const int bh   = ((id >> 3) >> 4) * 8 + (id & 7);   // 16 blocks/bh on one XCD
    const int p    = (id >> 3) & 15;                    // pair id 0..15
    const size_t base = (size_t)bh << 17;

    const int col = lane & 15;
    const int kg  = lane >> 4;
    const int srow = t >> 2;                       // staging row 0..63
    const int scol = (t & 3) << 4;                 // staging col 0/16/32/48
    const int b = bh / 12, h = bh % 12;

#pragma unroll
    for (int phase = 0; phase < 2; ++phase) {
        const int tile = phase ? p : (31 - p);     // heavy tile first
        const int q0   = tile << 6;
        const int nch  = tile + 1;

        // Q as B-frag (col' = q): same rows/addresses as before
        const ushort_t* pq = Q + base + (size_t)(q0 + 16 * w + col) * 64 + kg * 8;
        const short8 bq0 = *(const short8*)pq;
        const short8 bq1 = *(const short8*)(pq + 32);

        const int qcur = q0 + 16 * w + col;        // this lane's q row

        float l_run = 0.f;
        f32x4 o_acc[4];
#pragma unroll
        for (int vt = 0; vt < 4; ++vt) o_acc[vt] = (f32x4){0.f, 0.f, 0.f, 0.f};

        // preload chunk 0
        uint4 ka, kb, va, vb;
        {
            const ushort_t* pk = K  + base + (size_t)srow * 64 + scol;
            const ushort_t* pv = Vt + base + ((size_t)srow << 11) + scol;
            ka = *(const uint4*)pk; kb = *(const uint4*)(pk + 8);
            va = *(const uint4*)pv; vb = *(const uint4*)(pv + 8);
        }

        for (int c = 0; c < nch; ++c) {
            __syncthreads();   // previous chunk's LDS reads complete
            *(uint4*)&Ks[srow * KV_STRIDE + scol]     = ka;
            *(uint4*)&Ks[srow * KV_STRIDE + scol + 8] = kb;
            *(uint4*)&Vs[srow * KV_STRIDE + scol]     = va;
            *(uint4*)&Vs[srow * KV_STRIDE + scol + 8] = vb;
            __syncthreads();   // chunk staged

            if (c + 1 < nch) {   // prefetch next chunk (overlaps compute)
                const int k1 = (c + 1) << 6;
                const ushort_t* pk = K  + base + (size_t)(k1 + srow) * 64 + scol;
                const ushort_t* pv = Vt + base + ((size_t)srow << 11) + k1 + scol;
                ka = *(const uint4*)pk; kb = *(const uint4*)(pk + 8);
                va = *(const uint4*)pv; vb = *(const uint4*)(pv + 8);
            }

            // S^T = K (Q*0.125*log2e)^T : lane holds q=qcur, key=16kt+4kg+r
            f32x4 s[4];
            __builtin_amdgcn_s_setprio(1);
#pragma unroll
            for (int kt = 0; kt < 4; ++kt) {
                const ushort_t* pkf = &Ks[(kt * 16 + col) * KV_STRIDE + kg * 8];
                const short8 ak0 = *(const short8*)pkf;
                const short8 ak1 = *(const short8*)(pkf + 32);
                f32x4 acc = (f32x4){0.f, 0.f, 0.f, 0.f};
                acc = __builtin_amdgcn_mfma_f32_16x16x32_bf16(ak0, bq0, acc, 0, 0, 0);
                acc = __builtin_amdgcn_mfma_f32_16x16x32_bf16(ak1, bq1, acc, 0, 0, 0);
                s[kt] = acc;
            }
            __builtin_amdgcn_s_setprio(0);

            // P = exp2(S); causal mask only on the diagonal (last) chunk
            if (c == nch - 1) {
                const int k0 = c << 6;
#pragma unroll
                for (int kt = 0; kt < 4; ++kt)
#pragma unroll
                    for (int r = 0; r < 4; ++r) {
                        const int key = k0 + kt * 16 + 4 * kg + r;
                        s[kt][r] = (key > qcur) ? 0.f : exp2_hw(s[kt][r]);
                    }
            } else {
#pragma unroll
                for (int kt = 0; kt < 4; ++kt)
#pragma unroll
                    for (int r = 0; r < 4; ++r) s[kt][r] = exp2_hw(s[kt][r]);
            }
#pragma unroll
            for (int kt = 0; kt < 4; ++kt)
                l_run += (s[kt][0] + s[kt][1]) + (s[kt][2] + s[kt][3]);

            // ---- in-register P -> A-frag (replaces Ps LDS round-trip) ----
            unsigned int P2[4][2];
#pragma unroll
            for (int kt = 0; kt < 4; ++kt) {
                asm("v_cvt_pk_bf16_f32 %0, %1, %2"
                    : "=v"(P2[kt][0]) : "v"(s[kt][0]), "v"(s[kt][1]));
                asm("v_cvt_pk_bf16_f32 %0, %1, %2"
                    : "=v"(P2[kt][1]) : "v"(s[kt][2]), "v"(s[kt][3]));
            }
            const bool klo = (kg < 2);
            unsigned int X16[4], X32[4];
            X16[0] = klo ? P2[0][0] : P2[1][0];
            X16[1] = klo ? P2[0][1] : P2[1][1];
            X16[2] = klo ? P2[2][0] : P2[3][0];
            X16[3] = klo ? P2[2][1] : P2[3][1];
            X32[0] = klo ? P2[1][0] : P2[0][0];
            X32[1] = klo ? P2[1][1] : P2[0][1];
            X32[2] = klo ? P2[3][0] : P2[2][0];
            X32[3] = klo ? P2[3][1] : P2[2][1];
            unsigned int R16[4], R32[4], R48[4];
#pragma unroll
            for (int j = 0; j < 4; ++j) {
                R16[j] = (unsigned int)__shfl_xor((int)X16[j], 16);
                R32[j] = (unsigned int)__shfl_xor((int)X32[j], 32);
                R48[j] = (unsigned int)__shfl_xor((int)X32[j], 48);
            }
            unsigned int Fv[4], Sv[4];
#pragma unroll
            for (int j = 0; j < 4; ++j) {
                const unsigned int flo = (kg == 0) ? X16[j] : R48[j];
                const unsigned int fhi = (kg == 2) ? R32[j] : R16[j];
                Fv[j] = klo ? flo : fhi;
                const unsigned int slo = (kg == 0) ? R16[j] : R32[j];
                const unsigned int shi = (kg == 2) ? R48[j] : X16[j];
                Sv[j] = klo ? slo : shi;
            }
            union { unsigned int u[4]; short8 v; } A0, A1;
            A0.u[0] = Fv[0]; A0.u[1] = Fv[1]; A0.u[2] = Sv[0]; A0.u[3] = Sv[1];
            A1.u[0] = Fv[2]; A1.u[1] = Fv[3]; A1.u[2] = Sv[2]; A1.u[3] = Sv[3];
            const short8 pa0 = A0.v;
            const short8 pa1 = A1.v;

            // O += P V
            __builtin_amdgcn_s_setprio(1);
#pragma unroll
            for (int vt = 0; vt < 4; ++vt) {
                const ushort_t* pvf = &Vs[(vt * 16 + col) * KV_STRIDE + kg * 8];
                const short8 v0 = *(const short8*)pvf;
                const short8 v1 = *(const short8*)(pvf + 32);
                f32x4 o = o_acc[vt];
                o = __builtin_amdgcn_mfma_f32_16x16x32_bf16(pa0, v0, o, 0, 0, 0);
                o = __builtin_amdgcn_mfma_f32_16x16x32_bf16(pa1, v1, o, 0, 0, 0);
                o_acc[vt] = o;
            }
            __builtin_amdgcn_s_setprio(0);
        }

        // epilogue: finish l reduction (cross-kg), broadcast per output q
        float ls = l_run;
        ls += __shfl_xor(ls, 16);
        ls += __shfl_xor(ls, 32);
        const float linv = 1.f / ls;       // valid for q-col = lane&15
        float linv4[4];
#pragma unroll
        for (int r = 0; r < 4; ++r)
            linv4[r] = __shfl(linv, 4 * kg + r);   // lane j<16 holds q-col j
#pragma unroll
        for (int vt = 0; vt < 4; ++vt)
#pragma unroll
            for (int r = 0; r < 4; ++r) {
                const int q = q0 + 16 * w + 4 * kg + r;
                AO[((size_t)(b * 2048 + q)) * 768 + h * 64 + vt * 16 + col] =
                    f2b_fast(o_acc[vt][r] * linv4[r]);
            }
    }
}

extern "C" void kernel_launch(void* const* d_in, const int* in_sizes, int n_in,
                              void* d_out, int out_size, void* d_ws, size_t ws_size,
                              hipStream_t stream) {
    const float* hs = (const float*)d_in[0];
    const float* wq = (const float*)d_in[1];
    const float* bq = (const float*)d_in[2];
    const float* wk = (const float*)d_in[3];
    const float* bk = (const float*)d_in[4];
    const float* wv = (const float*)d_in[5];
    const float* bv = (const float*)d_in[6];
    const float* wo = (const float*)d_in[7];
    const float* bo = (const float*)d_in[8];
    float* out = (float*)d_out;

    const size_t NB = (size_t)8192 * 768;
    const size_t WN = (size_t)768 * 768;
    ushort_t* hsb = (ushort_t*)d_ws;        // aliased: becomes AO after QKV GEMMs
    ushort_t* Qb  = hsb + NB;
    ushort_t* Kb  = Qb + NB;
    ushort_t* Vtb = Kb + NB;                // V transposed [48][64][2048]
    ushort_t* wqb = Vtb + NB;
    ushort_t* wkb = wqb + WN;
    ushort_t* wvb = wkb + WN;
    ushort_t* wob = wvb + WN;
    ushort_t* AO  = hsb;                    // hs_bf16 dead once attn runs

    dim3 blk(256);
    convert_bf16<<<dim3(3072, 5), blk, 0, stream>>>(hs, wq, wk, wv, wo,
                                                    hsb, wqb, wkb, wvb, wob);
    gemm_mfma<0><<<dim3(1152), blk, 0, stream>>>(hsb, wqb, wkb, wvb,
                                                 bq, bk, bv, Qb, Kb, Vtb);
    attn_mfma<<<dim3(768), blk, 0, stream>>>(Qb, Kb, Vtb, AO);
    gemm_mfma<1><<<dim3(384), blk, 0, stream>>>(AO, wob, wob, wob,
                                                bo, bo, bo, out, out, out);
}